// Round 4
// baseline (150.619 us; speedup 1.0000x reference)
//
#include <hip/hip_runtime.h>
#include <math.h>

#define GH 224
#define GW 224
#define GN (GH*GW)          // 50176
#define NT 25
#define NCH 49              // 1024-px chunks for k_sums
#define LW 44               // w-tile width  (32 + 2 + 2*5)
#define LH 20               // w-tile height ( 8 + 2 + 2*5)
#define FW 34               // F-tile width  (32 + 2)
#define FH 10               // F-tile height ( 8 + 2)
#define NG 20               // distinct d2 values in 11x11 window
#define CAP 24576           // per-image (birth,death) list capacity

// ws layout (floats):
// [0..12)    image sums (atomicAdd; bound = 0.05*ws[idx])
// [16..40)   per-idx (mn_invbits, mx_bits) via uint atomicMax
// [48..60)   per-idx minima-list counters (int)
// [64..664)  lam[12][50]
// [1024..)   per-image lists: float2[CAP] each
#define WS_LIST 1024

// compile-time stable-sorted neighbor table (matches np.argsort(d2, kind="stable"))
// plus distance-group partition (equal-d2 runs).
struct NbrTbl { int off[121]; int gid[121]; float gd2[NG]; };
constexpr NbrTbl make_tbl() {
    NbrTbl t{};
    float ds[121] = {};
    for (int i = 0; i < 121; i++) {
        int dy = i / 11 - 5, dx = i % 11 - 5;
        int d2 = dy*dy + dx*dx;
        int rank = 0;
        for (int j = 0; j < 121; j++) {
            int ey = j / 11 - 5, ex = j % 11 - 5;
            int e2 = ey*ey + ex*ex;
            rank += (e2 < d2) || (e2 == d2 && j < i);
        }
        t.off[rank] = (dy + 5) * LW + (dx + 5);
        ds[rank]    = (float)d2;
    }
    int g = 0;
    t.gid[0] = 0; t.gd2[0] = ds[0];
    for (int r = 1; r < 121; r++) {
        if (ds[r] != ds[r-1]) { g++; t.gd2[g] = ds[r]; }
        t.gid[r] = g;
    }
    return t;
}
constexpr NbrTbl TBL = make_tbl();

__global__ __launch_bounds__(256) void k_sums(const float* __restrict__ in, float* __restrict__ ws) {
    int idx = blockIdx.x / NCH, chunk = blockIdx.x % NCH;
    int c = idx >> 2, b = idx & 3;
    const float4* w = (const float4*)(in + (size_t)(b*3 + c) * GN);
    float4 v = w[chunk*256 + threadIdx.x];
    float s = v.x + v.y + v.z + v.w;
    #pragma unroll
    for (int off = 32; off > 0; off >>= 1) s += __shfl_down(s, off);
    __shared__ float sh[4];
    if ((threadIdx.x & 63) == 0) sh[threadIdx.x >> 6] = s;
    __syncthreads();
    if (threadIdx.x == 0) atomicAdd(&ws[idx], sh[0] + sh[1] + sh[2] + sh[3]);
}

// DTM + 3x3 min/max + minima compaction, all fused per 32x8 tile.
__global__ __launch_bounds__(256) void k_dtm(const float* __restrict__ in, float* __restrict__ ws) {
    int idx  = blockIdx.x / 196;          // c*4+b
    int tblk = blockIdx.x % 196;
    int by = tblk / 7, bx = tblk % 7;     // interior origin (by*8, bx*32)
    int c = idx >> 2, b = idx & 3;
    const float* w = in + (size_t)(b*3 + c) * GN;

    __shared__ float tile[LH * LW];       // border-clamped w halo tile
    __shared__ float Ft[FH * FW];         // F with +1 halo (halo = clamped-coord F)
    __shared__ float sb[256], sd[256];    // compacted (birth, death)
    __shared__ int   lcnt, gbase;
    __shared__ float smn[4], smx[4];

    int gy0 = by*8 - 6, gx0 = bx*32 - 6;
    for (int i = threadIdx.x; i < LH * LW; i += 256) {
        int hr = i / LW, hc = i % LW;
        int gy = gy0 + hr; gy = gy < 0 ? 0 : (gy > GH-1 ? GH-1 : gy);
        int gx = gx0 + hc; gx = gx < 0 ? 0 : (gx > GW-1 ? GW-1 : gx);
        tile[i] = w[gy*GW + gx];
    }
    if (threadIdx.x == 0) lcnt = 0;
    __syncthreads();

    float bound = 0.05f * ws[idx];
    float mnv = INFINITY, mxv = -INFINITY;
    for (int i = threadIdx.x; i < FH * FW; i += 256) {
        int fy = i / FW, fx = i % FW;
        int gy = by*8  - 1 + fy; int cgy = gy < 0 ? 0 : (gy > GH-1 ? GH-1 : gy);
        int gx = bx*32 - 1 + fx; int cgx = gx < 0 ? 0 : (gx > GW-1 ? GW-1 : gx);
        const float* basep = tile + (cgy - gy0 - 5)*LW + (cgx - gx0 - 5);
        float grp[NG];
        #pragma unroll
        for (int g = 0; g < NG; g++) grp[g] = 0.f;
        #pragma unroll
        for (int j = 0; j < 121; j++) grp[TBL.gid[j]] += basep[TBL.off[j]];
        float cum = 0.f, acc = 0.f;
        #pragma unroll
        for (int g = 0; g < NG; g++) {
            float v = bound - cum;
            v = v < 0.f ? 0.f : v;
            v = v > grp[g] ? grp[g] : v;
            acc = fmaf(v, TBL.gd2[g], acc);
            cum += grp[g];
        }
        float f = sqrtf(acc / bound + 1e-12f);
        Ft[i] = f;
        mnv = fminf(mnv, f); mxv = fmaxf(mxv, f);
    }
    // fused global min/max of F (deterministic ordered-uint atomics; f > 0)
    #pragma unroll
    for (int off = 32; off > 0; off >>= 1) {
        mnv = fminf(mnv, __shfl_down(mnv, off));
        mxv = fmaxf(mxv, __shfl_down(mxv, off));
    }
    if ((threadIdx.x & 63) == 0) { smn[threadIdx.x>>6] = mnv; smx[threadIdx.x>>6] = mxv; }
    __syncthreads();                       // Ft complete + smn/smx ready
    if (threadIdx.x == 0) {
        float bm = fminf(fminf(smn[0], smn[1]), fminf(smn[2], smn[3]));
        float bX = fmaxf(fmaxf(smx[0], smx[1]), fmaxf(smx[2], smx[3]));
        atomicMax((unsigned int*)&ws[16 + 2*idx], ~__float_as_uint(bm));
        atomicMax((unsigned int*)&ws[17 + 2*idx],  __float_as_uint(bX));
    }

    // 3x3 is_min / death on interior, compact to LDS
    int tx = threadIdx.x & 31, ty = threadIdx.x >> 5;
    {
        const float* Fc = Ft + ty*FW + tx;   // window corner for (ty+1, tx+1)
        float f = Fc[FW + 1];
        float mn = f, mx = f;
        #pragma unroll
        for (int dy = 0; dy < 3; dy++)
            #pragma unroll
            for (int dx = 0; dx < 3; dx++) {
                float v = Fc[dy*FW + dx];
                mn = fminf(mn, v); mx = fmaxf(mx, v);
            }
        if (f <= mn) {
            int slot = atomicAdd(&lcnt, 1);
            sb[slot] = f; sd[slot] = mx;
        }
    }
    __syncthreads();
    if (threadIdx.x == 0) gbase = atomicAdd(&((int*)ws)[48 + idx], lcnt);
    __syncthreads();
    int n = lcnt, gb = gbase;
    float2* list = (float2*)(ws + WS_LIST) + (size_t)idx * CAP;
    for (int i = threadIdx.x; i < n; i += 256)
        if (gb + i < CAP) list[gb + i] = make_float2(sb[i], sd[i]);
}

__global__ __launch_bounds__(256) void k_top2(float* __restrict__ ws) {
    int idx = blockIdx.x / NT, t = blockIdx.x % NT;
    int nm = ((const int*)ws)[48 + idx]; nm = nm < CAP ? nm : CAP;
    float tmin = __uint_as_float(~((const unsigned int*)ws)[16 + 2*idx]);
    float tmax = __uint_as_float( ((const unsigned int*)ws)[17 + 2*idx]);
    float ts = tmin + (tmax - tmin) * ((float)t / 24.0f);
    const float2* list = (const float2*)(ws + WS_LIST) + (size_t)idx * CAP;
    float a0 = 0.f, a1 = 0.f;
    for (int i = threadIdx.x; i < nm; i += 256) {
        float2 p = list[i];
        float v = fmaxf(fminf(ts - p.x, p.y - ts), 0.f);
        float n0 = fmaxf(a0, v);
        a1 = fmaxf(a1, fminf(a0, v));
        a0 = n0;
    }
    #pragma unroll
    for (int off = 32; off > 0; off >>= 1) {
        float b0 = __shfl_down(a0, off);
        float b1 = __shfl_down(a1, off);
        float n0 = fmaxf(a0, b0);
        a1 = fmaxf(fminf(a0, b0), fmaxf(a1, b1));
        a0 = n0;
    }
    __shared__ float r0[4], r1[4];
    if ((threadIdx.x & 63) == 0) { r0[threadIdx.x>>6] = a0; r1[threadIdx.x>>6] = a1; }
    __syncthreads();
    if (threadIdx.x == 0) {
        float c0 = r0[0], c1 = r1[0];
        #pragma unroll
        for (int wv = 1; wv < 4; wv++) {
            float b0 = r0[wv], b1 = r1[wv];
            float n0 = fmaxf(c0, b0);
            c1 = fmaxf(fminf(c0, b0), fmaxf(c1, b1));
            c0 = n0;
        }
        ws[64 + (size_t)idx * 50 + t*2    ] = c0;
        ws[64 + (size_t)idx * 50 + t*2 + 1] = c1;
    }
}

__global__ __launch_bounds__(640) void k_head(const float* __restrict__ W1, const float* __restrict__ b1,
                                              const float* __restrict__ W2, const float* __restrict__ b2,
                                              const float* __restrict__ W3, const float* __restrict__ b3,
                                              const float* __restrict__ fcw, const float* __restrict__ fcb,
                                              const float* __restrict__ ws, float* __restrict__ out) {
    __shared__ float x[600];
    int tid = threadIdx.x;
    if (tid < 600) {
        int b = tid / 150, j = tid % 150, c = j / 50, o = j % 50;
        const float* Wc = (c == 0) ? W1 : (c == 1) ? W2 : W3;
        const float* bc = (c == 0) ? b1 : (c == 1) ? b2 : b3;
        const float* lam = ws + 64 + (size_t)(c*4 + b) * 50;
        float acc = bc[o];
        for (int f = 0; f < 50; f++) acc += lam[f] * Wc[o*50 + f];
        x[tid] = acc;
    }
    __syncthreads();
    if (tid < 150) {                     // signal = sum_b |x|
        float s = 0.f;
        for (int b = 0; b < 4; b++) s += fabsf(x[b*150 + tid]);
        out[28 + tid] = s;
    }
    if (tid >= 256 && tid < 284) {       // output = relu(x) @ fc_w.T + fc_b
        int t2 = tid - 256, b = t2 / 7, o = t2 % 7;
        float acc = fcb[o];
        for (int j = 0; j < 150; j++) acc += fmaxf(x[b*150 + j], 0.f) * fcw[o*150 + j];
        out[b*7 + o] = acc;
    }
}

extern "C" void kernel_launch(void* const* d_in, const int* in_sizes, int n_in,
                              void* d_out, int out_size, void* d_ws, size_t ws_size,
                              hipStream_t stream) {
    const float* in  = (const float*)d_in[0];
    const float* W1  = (const float*)d_in[1];
    const float* b1  = (const float*)d_in[2];
    const float* W2  = (const float*)d_in[3];
    const float* b2  = (const float*)d_in[4];
    const float* W3  = (const float*)d_in[5];
    const float* b3  = (const float*)d_in[6];
    const float* fcw = (const float*)d_in[7];
    const float* fcb = (const float*)d_in[8];
    float* ws  = (float*)d_ws;
    float* out = (float*)d_out;

    hipMemsetAsync(ws, 0, 64 * sizeof(float), stream);   // sums + minmax + counters
    k_sums <<<12 * NCH, 256, 0, stream>>>(in, ws);
    k_dtm  <<<12 * 196, 256, 0, stream>>>(in, ws);
    k_top2 <<<12 * NT,  256, 0, stream>>>(ws);
    k_head <<<1,        640, 0, stream>>>(W1, b1, W2, b2, W3, b3, fcw, fcb, ws, out);
}